// Round 1
// baseline (4549.483 us; speedup 1.0000x reference)
//
#include <hip/hip_runtime.h>
#include <hip/hip_bf16.h>

// SPINN: word GEMM + dataflow-reformulated TreeLSTM scan.
// B=128, L=64, E=512, H=512, T=127.

#define Bn 128
#define Ln 64
#define En 512
#define Hn 512
#define Tn 127
#define LEAF_ROWS (Bn*Ln)        // 8192 word rows (h_buf/c_buf)
#define NODE_ROWS (Bn*(Ln-1))    // 8064 reduce-node rows
#define TOT_ROWS (LEAF_ROWS+NODE_ROWS)

typedef __attribute__((ext_vector_type(8))) short bf16x8;
typedef __attribute__((ext_vector_type(4))) float f32x4;

static __device__ __forceinline__ float bf2f(unsigned short u){
  unsigned v = ((unsigned)u) << 16;
  float f; __builtin_memcpy(&f, &v, 4); return f;
}
static __device__ __forceinline__ unsigned short f2bf(float f){
  unsigned u; __builtin_memcpy(&u, &f, 4);
  u = u + 0x7FFFu + ((u >> 16) & 1u);   // round-nearest-even
  return (unsigned short)(u >> 16);
}
static __device__ __forceinline__ float sigm(float x){
  return 1.0f / (1.0f + __expf(-x));
}
static __device__ __forceinline__ float tanh_fast(float x){
  x = fminf(fmaxf(x, -15.0f), 15.0f);
  float t = __expf(2.0f * x);
  return (t - 1.0f) / (t + 1.0f);
}

// ---------------- convert / transpose helpers ----------------

__global__ void cvt_vec(const float* __restrict__ x, unsigned short* __restrict__ y, int n){
  int i = blockIdx.x * 256 + threadIdx.x;
  if (i < n) y[i] = f2bf(x[i]);
}

// dstT[(c)*DS + koff + r] = bf16(src[r*CS + c]); tiles of 32x32, block (32,8)
__global__ void transpose_cvt(const float* __restrict__ src, unsigned short* __restrict__ dstT,
                              int CS, int DS, int koff){
  __shared__ float tile[32][33];
  int c0 = blockIdx.x * 32, r0 = blockIdx.y * 32;
  int tx = threadIdx.x, ty = threadIdx.y;
  for (int i = ty; i < 32; i += 8) tile[i][tx] = src[(size_t)(r0 + i) * CS + c0 + tx];
  __syncthreads();
  for (int i = ty; i < 32; i += 8)
    dstT[(size_t)(c0 + i) * DS + koff + r0 + tx] = f2bf(tile[tx][i]);
}

// ---------------- control precompute (stack -> dataflow) ----------------
// One block, 128 threads; thread b simulates batch b's shift/reduce stack over
// tags (row indices into the combined leaf+node H/C arrays).
__global__ void precompute_ctrl(const int* __restrict__ trans,
                                int* __restrict__ srcL, int* __restrict__ srcR,
                                int* __restrict__ dstv, int* __restrict__ nred,
                                int* __restrict__ outsrc){
  int b = threadIdx.x;
  for (int t = b; t < Tn; t += 128) nred[t] = 0;
  __syncthreads();
  if (b >= Bn) return;
  int stack[Ln];
  int sp = 0, bp = 0, nodecnt = 0;
  for (int t = 0; t < Tn; t++){
    int act = trans[b * Tn + t];
    int ops = Tn - t;
    if (sp > ops) act = 2;                       // forced REDUCE (matches ref)
    if (act == 2){                               // REDUCE
      int ir = min(max(sp - 1, 0), Ln - 1);
      int il = min(max(sp - 2, 0), Ln - 1);
      int right = stack[ir], left = stack[il];
      int slot = atomicAdd(&nred[t], 1);
      srcL[t * Bn + slot] = left * Hn;           // element offsets (row*512)
      srcR[t * Bn + slot] = right * Hn;
      int noderow = LEAF_ROWS + b * (Ln - 1) + nodecnt;
      dstv[t * Bn + slot] = noderow * Hn;
      stack[il] = noderow;
      sp -= 1; nodecnt++;
    } else {                                     // SHIFT
      int iw = min(max(sp, 0), Ln - 1);
      stack[iw] = b * Ln + min(bp, Ln - 1);
      sp += 1; bp += 1;
    }
  }
  outsrc[b] = stack[min(max(sp - 1, 0), Ln - 1)] * Hn;
}

// ---------------- word GEMM: out = sentence @ W_word + b_word ----------------
// M=8192, K=512, N=1024. cols<512 -> HB (bf16 h), cols>=512 -> CF (f32 c).
// Block: Mtile=32, Ntile=64 (4 waves x 16 cols). A/B frags: lane&15 row/col,
// k = (lane>>4)*8 + j (consistent A/B mapping => correct under any HW k-perm).
__global__ __launch_bounds__(256) void word_gemm(
    const unsigned short* __restrict__ SB, const unsigned short* __restrict__ WwT,
    const float* __restrict__ b_word,
    unsigned short* __restrict__ HB, float* __restrict__ CF){
  int mt = blockIdx.x;            // 256 M-tiles
  int nt = blockIdx.y;            // 16 N-tiles
  int tid = threadIdx.x, w = tid >> 6, lane = tid & 63;
  int rc = lane & 15, lg = lane >> 4;
  int colbase = nt * 64 + w * 16;
  const unsigned short* ap0 = SB + (size_t)(mt * 32 + rc) * En + lg * 8;
  const unsigned short* ap1 = SB + (size_t)(mt * 32 + 16 + rc) * En + lg * 8;
  const unsigned short* bp  = WwT + (size_t)(colbase + rc) * En + lg * 8;
  f32x4 acc0 = {0.f,0.f,0.f,0.f}, acc1 = {0.f,0.f,0.f,0.f};
  #pragma unroll 4
  for (int k0 = 0; k0 < En; k0 += 32){
    bf16x8 a0 = *(const bf16x8*)(ap0 + k0);
    bf16x8 a1 = *(const bf16x8*)(ap1 + k0);
    bf16x8 bb = *(const bf16x8*)(bp + k0);
    acc0 = __builtin_amdgcn_mfma_f32_16x16x32_bf16(a0, bb, acc0, 0, 0, 0);
    acc1 = __builtin_amdgcn_mfma_f32_16x16x32_bf16(a1, bb, acc1, 0, 0, 0);
  }
  int col = colbase + rc;                 // C/D: col = lane&15 (+tile base)
  float bw = b_word[col];
  #pragma unroll
  for (int h = 0; h < 2; h++){
    f32x4 acc = h ? acc1 : acc0;
    #pragma unroll
    for (int q = 0; q < 4; q++){
      int row = mt * 32 + h * 16 + lg * 4 + q;   // C/D: row=(lane>>4)*4+reg
      float v = acc[q] + bw;
      if (col < Hn) HB[(size_t)row * Hn + col] = f2bf(v);
      else          CF[(size_t)row * Hn + (col - Hn)] = v;
    }
  }
}

// ---------------- per-step reduce kernel ----------------
// Compacted active rows (nred[t]); M-tile 32, u-tile 64; each wave computes all
// 5 gates for its 16-u strip (K=1024 = hl|hr), then fused LSTM + scatter.
__global__ __launch_bounds__(256) void step_kernel(
    unsigned short* __restrict__ HB, float* __restrict__ CF,
    const unsigned short* __restrict__ WT, const float* __restrict__ b_red,
    const int* __restrict__ srcL, const int* __restrict__ srcR,
    const int* __restrict__ dstv, const int* __restrict__ nredp, int t){
  int nr = nredp[t];
  int bx = blockIdx.x;
  int mt = bx >> 3, ut = bx & 7;
  if (mt * 32 >= nr) return;
  int tid = threadIdx.x, w = tid >> 6, lane = tid & 63;
  int rc = lane & 15, lg = lane >> 4;
  int u0 = ut * 64 + w * 16;
  const int* sL = srcL + t * Bn;
  const int* sR = srcR + t * Bn;
  const int* dl = dstv + t * Bn;
  int i0c = min(mt * 32 + rc, nr - 1);
  int i1c = min(mt * 32 + 16 + rc, nr - 1);
  const unsigned short* aL0 = HB + sL[i0c] + lg * 8;
  const unsigned short* aL1 = HB + sL[i1c] + lg * 8;
  const unsigned short* aR0 = HB + sR[i0c] + lg * 8;
  const unsigned short* aR1 = HB + sR[i1c] + lg * 8;
  const unsigned short* bp[5];
  #pragma unroll
  for (int gi = 0; gi < 5; gi++)
    bp[gi] = WT + (size_t)(gi * Hn + u0 + rc) * 1024 + lg * 8;

  f32x4 acc[5][2];
  #pragma unroll
  for (int gi = 0; gi < 5; gi++){
    acc[gi][0] = (f32x4){0.f,0.f,0.f,0.f};
    acc[gi][1] = (f32x4){0.f,0.f,0.f,0.f};
  }
  #pragma unroll 4
  for (int k0 = 0; k0 < 512; k0 += 32){            // left child half of K
    bf16x8 a0 = *(const bf16x8*)(aL0 + k0);
    bf16x8 a1 = *(const bf16x8*)(aL1 + k0);
    #pragma unroll
    for (int gi = 0; gi < 5; gi++){
      bf16x8 bb = *(const bf16x8*)(bp[gi] + k0);
      acc[gi][0] = __builtin_amdgcn_mfma_f32_16x16x32_bf16(a0, bb, acc[gi][0], 0, 0, 0);
      acc[gi][1] = __builtin_amdgcn_mfma_f32_16x16x32_bf16(a1, bb, acc[gi][1], 0, 0, 0);
    }
  }
  #pragma unroll 4
  for (int k0 = 512; k0 < 1024; k0 += 32){         // right child half of K
    bf16x8 a0 = *(const bf16x8*)(aR0 + (k0 - 512));
    bf16x8 a1 = *(const bf16x8*)(aR1 + (k0 - 512));
    #pragma unroll
    for (int gi = 0; gi < 5; gi++){
      bf16x8 bb = *(const bf16x8*)(bp[gi] + k0);
      acc[gi][0] = __builtin_amdgcn_mfma_f32_16x16x32_bf16(a0, bb, acc[gi][0], 0, 0, 0);
      acc[gi][1] = __builtin_amdgcn_mfma_f32_16x16x32_bf16(a1, bb, acc[gi][1], 0, 0, 0);
    }
  }
  // fused bias + TreeLSTM + scatter
  int colu = u0 + rc;                              // hidden unit index
  float bg  = b_red[colu];
  float bi  = b_red[Hn + colu];
  float bf1 = b_red[2 * Hn + colu];
  float bf2 = b_red[3 * Hn + colu];
  float bo  = b_red[4 * Hn + colu];
  #pragma unroll
  for (int h = 0; h < 2; h++){
    #pragma unroll
    for (int q = 0; q < 4; q++){
      int i = mt * 32 + h * 16 + lg * 4 + q;
      if (i < nr){
        int offL = sL[i], offR = sR[i], offD = dl[i];
        float gv  = tanh_fast(acc[0][h][q] + bg);
        float iv  = sigm(acc[1][h][q] + bi);
        float f1v = sigm(acc[2][h][q] + bf1);
        float f2v = sigm(acc[3][h][q] + bf2);
        float ov  = sigm(acc[4][h][q] + bo);
        float cl = CF[offL + colu], cr = CF[offR + colu];
        float cv = gv * iv + f1v * cl + f2v * cr;
        float hv = ov * tanh_fast(cv);
        CF[offD + colu] = cv;
        HB[offD + colu] = f2bf(hv);
      }
    }
  }
}

// ---------------- final gather ----------------
__global__ void gather_out(const unsigned short* __restrict__ HB,
                           const int* __restrict__ outsrc, float* __restrict__ out){
  int b = blockIdx.x, u = threadIdx.x;
  out[b * Hn + u] = bf2f(HB[outsrc[b] + u]);
}

// ---------------- launch ----------------
extern "C" void kernel_launch(void* const* d_in, const int* in_sizes, int n_in,
                              void* d_out, int out_size, void* d_ws, size_t ws_size,
                              hipStream_t stream){
  (void)in_sizes; (void)n_in; (void)out_size; (void)ws_size;
  const float* sentence = (const float*)d_in[0];
  const int*   trans    = (const int*)d_in[1];
  const float* W_word   = (const float*)d_in[2];
  const float* b_word   = (const float*)d_in[3];
  const float* W_left   = (const float*)d_in[4];
  const float* W_right  = (const float*)d_in[5];
  const float* b_red    = (const float*)d_in[6];

  char* ws = (char*)d_ws;
  size_t off = 0;
  auto alloc = [&](size_t bytes) -> void* {
    void* p = ws + off;
    off += (bytes + 255) & ~((size_t)255);
    return p;
  };
  unsigned short* HB  = (unsigned short*)alloc((size_t)TOT_ROWS * Hn * 2); // bf16 h (leaf+node)
  float*          CF  = (float*)alloc((size_t)TOT_ROWS * Hn * 4);          // f32 c (leaf+node)
  unsigned short* WT  = (unsigned short*)alloc((size_t)2560 * 1024 * 2);   // [W_left;W_right]^T bf16
  unsigned short* SB  = (unsigned short*)alloc((size_t)LEAF_ROWS * En * 2);// sentence bf16
  unsigned short* WwT = (unsigned short*)alloc((size_t)1024 * En * 2);     // W_word^T bf16
  int* srcL   = (int*)alloc((size_t)Tn * Bn * 4);
  int* srcR   = (int*)alloc((size_t)Tn * Bn * 4);
  int* dstv   = (int*)alloc((size_t)Tn * Bn * 4);
  int* nred   = (int*)alloc((size_t)Tn * 4);
  int* outsrc = (int*)alloc((size_t)Bn * 4);

  cvt_vec<<<(LEAF_ROWS * En) / 256, 256, 0, stream>>>(sentence, SB, LEAF_ROWS * En);
  transpose_cvt<<<dim3(1024 / 32, En / 32), dim3(32, 8), 0, stream>>>(W_word, WwT, 1024, En, 0);
  transpose_cvt<<<dim3(2560 / 32, Hn / 32), dim3(32, 8), 0, stream>>>(W_left, WT, 2560, 1024, 0);
  transpose_cvt<<<dim3(2560 / 32, Hn / 32), dim3(32, 8), 0, stream>>>(W_right, WT, 2560, 1024, 512);
  precompute_ctrl<<<1, 128, 0, stream>>>(trans, srcL, srcR, dstv, nred, outsrc);
  word_gemm<<<dim3(LEAF_ROWS / 32, 1024 / 64), 256, 0, stream>>>(SB, WwT, b_word, HB, CF);
  for (int t = 0; t < Tn; t++)
    step_kernel<<<32, 256, 0, stream>>>(HB, CF, WT, b_red, srcL, srcR, dstv, nred, t);
  gather_out<<<Bn, Hn, 0, stream>>>(HB, outsrc, (float*)d_out);
}

// Round 2
// 1284.100 us; speedup vs baseline: 3.5429x; 3.5429x over previous
//
#include <hip/hip_runtime.h>
#include <hip/hip_bf16.h>

// SPINN: word GEMM + level-scheduled TreeLSTM dataflow.
// B=128, L=64, E=512, H=512, T=127.

#define Bn 128
#define Ln 64
#define En 512
#define Hn 512
#define Tn 127
#define LEAF_ROWS (Bn*Ln)        // 8192 word rows
#define NODE_ROWS (Bn*(Ln-1))    // 8064 reduce-node rows
#define TOT_ROWS (LEAF_ROWS+NODE_ROWS)
#define CAPL 4096                // max rows in any level (level 1: 128*32)
#define NLVL 64

typedef __attribute__((ext_vector_type(8))) short bf16x8;
typedef __attribute__((ext_vector_type(4))) float f32x4;

static __device__ __forceinline__ float bf2f(unsigned short u){
  unsigned v = ((unsigned)u) << 16;
  float f; __builtin_memcpy(&f, &v, 4); return f;
}
static __device__ __forceinline__ unsigned short f2bf(float f){
  unsigned u; __builtin_memcpy(&u, &f, 4);
  u = u + 0x7FFFu + ((u >> 16) & 1u);   // round-nearest-even
  return (unsigned short)(u >> 16);
}
static __device__ __forceinline__ float sigm(float x){
  return 1.0f / (1.0f + __expf(-x));
}
static __device__ __forceinline__ float tanh_fast(float x){
  x = fminf(fmaxf(x, -15.0f), 15.0f);
  float t = __expf(2.0f * x);
  return (t - 1.0f) / (t + 1.0f);
}

// ---------------- convert / transpose helpers ----------------

__global__ void cvt_vec4(const float4* __restrict__ x, ushort4* __restrict__ y, int n4){
  int i = blockIdx.x * 256 + threadIdx.x;
  if (i < n4){
    float4 v = x[i];
    ushort4 o;
    o.x = f2bf(v.x); o.y = f2bf(v.y); o.z = f2bf(v.z); o.w = f2bf(v.w);
    y[i] = o;
  }
}

// dstT[c*DS + koff + r] = bf16(src[r*CS + c]); tiles 32x32, block (32,8)
__global__ void transpose_cvt(const float* __restrict__ src, unsigned short* __restrict__ dstT,
                              int CS, int DS, int koff){
  __shared__ float tile[32][33];
  int c0 = blockIdx.x * 32, r0 = blockIdx.y * 32;
  int tx = threadIdx.x, ty = threadIdx.y;
  for (int i = ty; i < 32; i += 8) tile[i][tx] = src[(size_t)(r0 + i) * CS + c0 + tx];
  __syncthreads();
  for (int i = ty; i < 32; i += 8)
    dstT[(size_t)(c0 + i) * DS + koff + r0 + tx] = f2bf(tile[tx][i]);
}

// ---------------- control precompute: stack sim -> per-LEVEL dataflow ----------------
// One block, 128 threads, stacks in LDS (packed: tag | level<<20).
// Node level = 1 + max(level(left), level(right)); same-level nodes are independent.
__global__ void precompute_ctrl(const int* __restrict__ trans,
                                int* __restrict__ srcL, int* __restrict__ srcR,
                                int* __restrict__ dstv, int* __restrict__ cnt,
                                int* __restrict__ outsrc){
  __shared__ int stk[Bn][Ln];    // 32 KB
  int b = threadIdx.x;
  if (b < NLVL) cnt[b] = 0;
  __syncthreads();
  int sp = 0, bp = 0, nodecnt = 0;
  for (int t = 0; t < Tn; t++){
    int act = trans[b * Tn + t];
    int ops = Tn - t;
    if (sp > ops) act = 2;                       // forced REDUCE (matches ref)
    if (act == 2){                               // REDUCE
      int R = stk[b][sp - 1], L = stk[b][sp - 2];
      int lvl = max(R >> 20, L >> 20) + 1;       // 1..63
      int slot = atomicAdd(&cnt[lvl], 1);
      srcL[lvl * CAPL + slot] = (L & 0xFFFFF) * Hn;
      srcR[lvl * CAPL + slot] = (R & 0xFFFFF) * Hn;
      int noderow = LEAF_ROWS + b * (Ln - 1) + nodecnt;
      dstv[lvl * CAPL + slot] = noderow * Hn;
      stk[b][sp - 2] = noderow | (lvl << 20);
      sp -= 1; nodecnt++;
    } else {                                     // SHIFT (leaf: level 0)
      stk[b][sp] = b * Ln + min(bp, Ln - 1);
      sp += 1; bp += 1;
    }
  }
  outsrc[b] = (stk[b][max(sp - 1, 0)] & 0xFFFFF) * Hn;
}

// ---------------- word GEMM: out = sentence @ W_word + b_word ----------------
// M=8192, K=512, N=1024. Block tile 64M x 128N, 4 waves as 2x2 (2 M-frags, 4 N-strips).
// grid x = N-tile (8) -> XCD-affine: B slice (128 cols, 128KB) L2-resident per XCD.
__global__ __launch_bounds__(256) void word_gemm(
    const unsigned short* __restrict__ SB, const unsigned short* __restrict__ WwT,
    const float* __restrict__ b_word,
    unsigned short* __restrict__ HB, float* __restrict__ CF){
  int nt = blockIdx.x;            // 8 N-tiles (XCD-affine)
  int mt = blockIdx.y;            // 128 M-tiles
  int tid = threadIdx.x, w = tid >> 6, lane = tid & 63;
  int wm = w >> 1, wn = w & 1;
  int rc = lane & 15, lg = lane >> 4;
  const unsigned short* ap0 = SB + (size_t)(mt * 64 + wm * 32 + rc) * En + lg * 8;
  const unsigned short* ap1 = ap0 + (size_t)16 * En;
  const unsigned short* bp0 = WwT + (size_t)(nt * 128 + wn * 64 + rc) * En + lg * 8;
  f32x4 acc[2][4];
  #pragma unroll
  for (int h = 0; h < 2; h++)
    #pragma unroll
    for (int nb = 0; nb < 4; nb++) acc[h][nb] = (f32x4){0.f,0.f,0.f,0.f};
  #pragma unroll 2
  for (int k0 = 0; k0 < En; k0 += 32){
    bf16x8 a0 = *(const bf16x8*)(ap0 + k0);
    bf16x8 a1 = *(const bf16x8*)(ap1 + k0);
    #pragma unroll
    for (int nb = 0; nb < 4; nb++){
      bf16x8 bb = *(const bf16x8*)(bp0 + (size_t)nb * 16 * En + k0);
      acc[0][nb] = __builtin_amdgcn_mfma_f32_16x16x32_bf16(a0, bb, acc[0][nb], 0, 0, 0);
      acc[1][nb] = __builtin_amdgcn_mfma_f32_16x16x32_bf16(a1, bb, acc[1][nb], 0, 0, 0);
    }
  }
  #pragma unroll
  for (int nb = 0; nb < 4; nb++){
    int col = nt * 128 + wn * 64 + nb * 16 + rc;
    float bw = b_word[col];
    #pragma unroll
    for (int h = 0; h < 2; h++){
      #pragma unroll
      for (int q = 0; q < 4; q++){
        int row = mt * 64 + wm * 32 + h * 16 + lg * 4 + q;
        float v = acc[h][nb][q] + bw;
        if (col < Hn) HB[(size_t)row * Hn + col] = f2bf(v);
        else          CF[(size_t)row * Hn + (col - Hn)] = v;
      }
    }
  }
}

// ---------------- per-level reduce kernel ----------------
// Active rows for this level (cnt[lvl]); M-block = 16*MF rows; grid x = 8 u-tiles
// (XCD-affine: each XCD's 640KB weight slice stays L2-resident across levels).
// Each wave: 16 u's x 5 gates x MF M-frags, K=1024 (hl | hr), fused LSTM + scatter.
template<int MF>
__global__ __launch_bounds__(256) void level_kernel(
    unsigned short* __restrict__ HB, float* __restrict__ CF,
    const unsigned short* __restrict__ WT, const float* __restrict__ b_red,
    const int* __restrict__ srcL, const int* __restrict__ srcR,
    const int* __restrict__ dstv, const int* __restrict__ cnt, int lvl){
  int nr = cnt[lvl];
  int ut = blockIdx.x;             // 0..7
  int mt = blockIdx.y;
  const int MB = 16 * MF;
  if (mt * MB >= nr) return;
  int tid = threadIdx.x, w = tid >> 6, lane = tid & 63;
  int rc = lane & 15, lg = lane >> 4;
  int u0 = ut * 64 + w * 16;
  const int* sL = srcL + lvl * CAPL;
  const int* sR = srcR + lvl * CAPL;
  const int* dl = dstv + lvl * CAPL;
  int offL[MF], offR[MF];
  #pragma unroll
  for (int h = 0; h < MF; h++){
    int i = min(mt * MB + h * 16 + rc, nr - 1);
    offL[h] = sL[i]; offR[h] = sR[i];
  }
  const unsigned short* bpp = WT + (size_t)(u0 + rc) * 1024 + lg * 8;

  f32x4 acc[5][MF];
  #pragma unroll
  for (int gi = 0; gi < 5; gi++)
    #pragma unroll
    for (int h = 0; h < MF; h++) acc[gi][h] = (f32x4){0.f,0.f,0.f,0.f};

  #pragma unroll 2
  for (int k0 = 0; k0 < 512; k0 += 32){            // left-child half of K
    bf16x8 a[MF];
    #pragma unroll
    for (int h = 0; h < MF; h++) a[h] = *(const bf16x8*)(HB + offL[h] + lg * 8 + k0);
    #pragma unroll
    for (int gi = 0; gi < 5; gi++){
      bf16x8 bb = *(const bf16x8*)(bpp + (size_t)gi * Hn * 1024 + k0);
      #pragma unroll
      for (int h = 0; h < MF; h++)
        acc[gi][h] = __builtin_amdgcn_mfma_f32_16x16x32_bf16(a[h], bb, acc[gi][h], 0, 0, 0);
    }
  }
  #pragma unroll 2
  for (int k0 = 0; k0 < 512; k0 += 32){            // right-child half of K
    bf16x8 a[MF];
    #pragma unroll
    for (int h = 0; h < MF; h++) a[h] = *(const bf16x8*)(HB + offR[h] + lg * 8 + k0);
    #pragma unroll
    for (int gi = 0; gi < 5; gi++){
      bf16x8 bb = *(const bf16x8*)(bpp + (size_t)gi * Hn * 1024 + 512 + k0);
      #pragma unroll
      for (int h = 0; h < MF; h++)
        acc[gi][h] = __builtin_amdgcn_mfma_f32_16x16x32_bf16(a[h], bb, acc[gi][h], 0, 0, 0);
    }
  }
  // fused bias + TreeLSTM + scatter
  int colu = u0 + rc;
  float bg  = b_red[colu];
  float bi  = b_red[Hn + colu];
  float bf1 = b_red[2 * Hn + colu];
  float bf2 = b_red[3 * Hn + colu];
  float bo  = b_red[4 * Hn + colu];
  #pragma unroll
  for (int h = 0; h < MF; h++){
    #pragma unroll
    for (int q = 0; q < 4; q++){
      int i = mt * MB + h * 16 + lg * 4 + q;
      if (i < nr){
        int oL = sL[i], oR = sR[i], oD = dl[i];
        float gv  = tanh_fast(acc[0][h][q] + bg);
        float iv  = sigm(acc[1][h][q] + bi);
        float f1v = sigm(acc[2][h][q] + bf1);
        float f2v = sigm(acc[3][h][q] + bf2);
        float ov  = sigm(acc[4][h][q] + bo);
        float cl = CF[oL + colu], cr = CF[oR + colu];
        float cv = gv * iv + f1v * cl + f2v * cr;
        float hv = ov * tanh_fast(cv);
        CF[oD + colu] = cv;
        HB[oD + colu] = f2bf(hv);
      }
    }
  }
}

// ---------------- final gather ----------------
__global__ void gather_out(const unsigned short* __restrict__ HB,
                           const int* __restrict__ outsrc, float* __restrict__ out){
  int b = blockIdx.x, u = threadIdx.x;
  out[b * Hn + u] = bf2f(HB[outsrc[b] + u]);
}

// ---------------- launch ----------------
extern "C" void kernel_launch(void* const* d_in, const int* in_sizes, int n_in,
                              void* d_out, int out_size, void* d_ws, size_t ws_size,
                              hipStream_t stream){
  (void)in_sizes; (void)n_in; (void)out_size; (void)ws_size;
  const float* sentence = (const float*)d_in[0];
  const int*   trans    = (const int*)d_in[1];
  const float* W_word   = (const float*)d_in[2];
  const float* b_word   = (const float*)d_in[3];
  const float* W_left   = (const float*)d_in[4];
  const float* W_right  = (const float*)d_in[5];
  const float* b_red    = (const float*)d_in[6];

  char* ws = (char*)d_ws;
  size_t off = 0;
  auto alloc = [&](size_t bytes) -> void* {
    void* p = ws + off;
    off += (bytes + 255) & ~((size_t)255);
    return p;
  };
  unsigned short* HB  = (unsigned short*)alloc((size_t)TOT_ROWS * Hn * 2); // bf16 h
  float*          CF  = (float*)alloc((size_t)TOT_ROWS * Hn * 4);          // f32 c
  unsigned short* WT  = (unsigned short*)alloc((size_t)2560 * 1024 * 2);   // [W_left;W_right]^T bf16
  unsigned short* SB  = (unsigned short*)alloc((size_t)LEAF_ROWS * En * 2);// sentence bf16
  unsigned short* WwT = (unsigned short*)alloc((size_t)1024 * En * 2);     // W_word^T bf16
  int* srcL   = (int*)alloc((size_t)NLVL * CAPL * 4);
  int* srcR   = (int*)alloc((size_t)NLVL * CAPL * 4);
  int* dstv   = (int*)alloc((size_t)NLVL * CAPL * 4);
  int* cnt    = (int*)alloc((size_t)NLVL * 4);
  int* outsrc = (int*)alloc((size_t)Bn * 4);

  cvt_vec4<<<(LEAF_ROWS * En / 4) / 256, 256, 0, stream>>>((const float4*)sentence, (ushort4*)SB, LEAF_ROWS * En / 4);
  transpose_cvt<<<dim3(1024 / 32, En / 32), dim3(32, 8), 0, stream>>>(W_word, WwT, 1024, En, 0);
  transpose_cvt<<<dim3(2560 / 32, Hn / 32), dim3(32, 8), 0, stream>>>(W_left, WT, 2560, 1024, 0);
  transpose_cvt<<<dim3(2560 / 32, Hn / 32), dim3(32, 8), 0, stream>>>(W_right, WT, 2560, 1024, 512);
  precompute_ctrl<<<1, 128, 0, stream>>>(trans, srcL, srcR, dstv, cnt, outsrc);
  word_gemm<<<dim3(8, LEAF_ROWS / 64), 256, 0, stream>>>(SB, WwT, b_word, HB, CF);
  for (int l = 1; l < NLVL; l++){
    int capl = Bn * (Ln / (l + 1));               // height-l nodes span >= l+1 leaves
    if (l <= 6)
      level_kernel<4><<<dim3(8, (capl + 63) / 64), 256, 0, stream>>>(HB, CF, WT, b_red, srcL, srcR, dstv, cnt, l);
    else
      level_kernel<1><<<dim3(8, (capl + 15) / 16), 256, 0, stream>>>(HB, CF, WT, b_red, srcL, srcR, dstv, cnt, l);
  }
  gather_out<<<Bn, Hn, 0, stream>>>(HB, outsrc, (float*)d_out);
}